// Round 14
// baseline (109.799 us; speedup 1.0000x reference)
//
#include <hip/hip_runtime.h>
#include <stdint.h>

#define HW 3136
#define IMGW 56
#define NIMG 32

static __device__ __forceinline__ int dot4i8(int a, int b, int c) {
#if __has_builtin(__builtin_amdgcn_sdot4)
  return __builtin_amdgcn_sdot4(a, b, c, false);
#else
  c += (int)(int8_t)(a      ) * (int)(int8_t)(b      );
  c += (int)(int8_t)(a >>  8) * (int)(int8_t)(b >>  8);
  c += (int)(int8_t)(a >> 16) * (int)(int8_t)(b >> 16);
  c += (int)(int8_t)(a >> 24) * (int)(int8_t)(b >> 24);
  return c;
#endif
}

// BN: round((alpha*acc + off) * 2^-10), clamp to [-128,127]. Exact f32 ops,
// no contraction (matches numpy mul/add/round-half-even chain bit-exactly).
static __device__ __forceinline__ float bnq(float alpha, float off, int acc) {
  float t = __fmul_rn(alpha, (float)acc);
  t = __fadd_rn(t, off);
  t = __fmul_rn(t, 0x1p-10f);
  float r = rintf(t);
  return fminf(fmaxf(r, -128.0f), 127.0f);
}

// ---------------- prep: pack weights + fold BN constants ----------------
__global__ void prep_kernel(
    const int* __restrict__ s1, const int* __restrict__ m1,
    const float* __restrict__ a1, const float* __restrict__ b1, const int* __restrict__ q1,
    const int* __restrict__ s2, const int* __restrict__ m2,
    const float* __restrict__ a2, const float* __restrict__ b2, const int* __restrict__ q2,
    const int* __restrict__ s3, const int* __restrict__ m3,
    const float* __restrict__ a3, const float* __restrict__ b3, const int* __restrict__ q3,
    int* __restrict__ w1p, int* __restrict__ w2p, int* __restrict__ w3p,
    float* __restrict__ a1p, float* __restrict__ o1p,
    float* __restrict__ a2p, float* __restrict__ o2p,
    float* __restrict__ a3p, float* __restrict__ o3p)
{
  int t = blockIdx.x * blockDim.x + threadIdx.x;
  int nthr = gridDim.x * blockDim.x;

  // w1p[cg*64 + co] packs input channels cg*4..cg*4+3 for output co (conv1: 64x256)
  for (int i = t; i < 64 * 64; i += nthr) {
    int cg = i >> 6, co = i & 63;
    int p = 0;
    for (int j = 0; j < 4; ++j) {
      int ci = cg * 4 + j;
      int idx = co * 256 + ci;
      int w = m1[idx] * (1 << s1[idx]);
      p |= (w & 0xFF) << (8 * j);
    }
    w1p[i] = p;
  }
  // w2p layout: i = ((s*9+tap)*16+cg)*16 + cc*4 + j
  for (int i = t; i < 4 * 9 * 16 * 16; i += nthr) {
    int j = i & 3;
    int cc = (i >> 2) & 3;
    int cg = (i >> 4) & 15;
    int rest = i >> 8;        // s*9 + tap
    int tap = rest % 9;
    int s = rest / 9;
    int co = s * 16 + cc * 4 + j;
    int ky = tap / 3, kx = tap % 3;
    int p = 0;
    for (int jj = 0; jj < 4; ++jj) {
      int ci = cg * 4 + jj;
      int idx = ((co * 64 + ci) * 3 + ky) * 3 + kx;
      int w = m2[idx] * (1 << s2[idx]);
      p |= (w & 0xFF) << (8 * jj);
    }
    w2p[i] = p;
  }
  // w3p[(co4*16+cg)*4 + j]
  for (int i = t; i < 64 * 16 * 4; i += nthr) {
    int j = i & 3;
    int cg = (i >> 2) & 15;
    int co4 = i >> 6;
    int co = co4 * 4 + j;
    int p = 0;
    for (int jj = 0; jj < 4; ++jj) {
      int ci = cg * 4 + jj;
      int idx = co * 64 + ci;
      int w = m3[idx] * (1 << s3[idx]);
      p |= (w & 0xFF) << (8 * jj);
    }
    w3p[i] = p;
  }
  for (int i = t; i < 64; i += nthr) {
    a1p[i] = a1[i];
    o1p[i] = __fmul_rn(b1[i], exp2f((float)q1[i] + 10.0f));
    a2p[i] = a2[i];
    o2p[i] = __fmul_rn(b2[i], exp2f((float)q2[i] + 10.0f));
  }
  for (int i = t; i < 256; i += nthr) {
    a3p[i] = a3[i];
    o3p[i] = __fmul_rn(b3[i], exp2f((float)q3[i] + 10.0f));
  }
}

// ---------------- k01: pack x -> int8 (global x8p + LDS) then conv1 ----------------
// Phase B conv1: unroll-by-4 (4 copies x ~0.35 KB = ~1.4 KB) — R14 middle
// point between full-unroll (I$ bust) and rolled (per-iter lgkm stall).
__global__ __launch_bounds__(256) void k01_pack_conv1(
    const float* __restrict__ x,
    const int* __restrict__ w1p,
    const float* __restrict__ a1p, const float* __restrict__ o1p,
    int* __restrict__ x8p, int* __restrict__ y1p)
{
  __shared__ int ldsx[64 * 68];   // 17408 B

  int tid = threadIdx.x;

  // ---- Phase A: load + pack ----
  {
    int o = tid & 3;
    int p = tid >> 2;
    size_t pg = (size_t)blockIdx.x * 64 + p;
    int n = (int)(pg / HW);
    int pos = (int)(pg - (size_t)n * HW);
    const float* xb = x + ((size_t)n * 256 + o * 64) * HW + pos;

    float f[64];
#pragma unroll
    for (int k = 0; k < 64; ++k) f[k] = xb[(size_t)k * HW];
    __builtin_amdgcn_sched_barrier(0);  // all 64 loads before any consumer

    int4 ov[4];
#pragma unroll
    for (int g = 0; g < 4; ++g) {
      int wds[4];
#pragma unroll
      for (int wdi = 0; wdi < 4; ++wdi) {
        int c0 = g * 16 + wdi * 4;
        wds[wdi] = ((int)f[c0] & 0xFF) | (((int)f[c0 + 1] & 0xFF) << 8) |
                   (((int)f[c0 + 2] & 0xFF) << 16) | (((int)f[c0 + 3] & 0xFF) << 24);
      }
      ov[g].x = wds[0]; ov[g].y = wds[1]; ov[g].z = wds[2]; ov[g].w = wds[3];
    }

    int* gb = x8p + pg * 64 + o * 16;
#pragma unroll
    for (int g = 0; g < 4; ++g) ((int4*)gb)[g] = ov[g];
    int* lb = &ldsx[p * 68 + o * 16];
#pragma unroll
    for (int g = 0; g < 4; ++g) *(int4*)(lb + g * 4) = ov[g];
  }
  __syncthreads();

  // ---- Phase B: conv1 from LDS (unroll 4: next-chunk s_loads hoist under dot4s) ----
  int lane = tid & 63;
  int s = __builtin_amdgcn_readfirstlane(tid >> 6);
  size_t pidx = (size_t)blockIdx.x * 64 + lane;

  int acc[16];
#pragma unroll
  for (int i = 0; i < 16; ++i) acc[i] = 0;

  const int* lx = &ldsx[lane * 68];
#pragma unroll 4
  for (int m = 0; m < 16; ++m) {
    int4 xm = *(const int4*)(lx + m * 4);
#pragma unroll
    for (int e = 0; e < 4; ++e) {
      int xv = e == 0 ? xm.x : (e == 1 ? xm.y : (e == 2 ? xm.z : xm.w));
      const int4* wr = (const int4*)(w1p + (m * 4 + e) * 64 + s * 16);
#pragma unroll
      for (int c = 0; c < 4; ++c) {
        int4 wv = wr[c];
        acc[c * 4 + 0] = dot4i8(xv, wv.x, acc[c * 4 + 0]);
        acc[c * 4 + 1] = dot4i8(xv, wv.y, acc[c * 4 + 1]);
        acc[c * 4 + 2] = dot4i8(xv, wv.z, acc[c * 4 + 2]);
        acc[c * 4 + 3] = dot4i8(xv, wv.w, acc[c * 4 + 3]);
      }
    }
  }

  int op[4];
#pragma unroll
  for (int c = 0; c < 4; ++c) {
    int p = 0;
#pragma unroll
    for (int j = 0; j < 4; ++j) {
      int co = s * 16 + c * 4 + j;
      float r = bnq(a1p[co], o1p[co], acc[c * 4 + j]);
      int v = (int)r;
      if (v < 0) v = 0;  // relu
      p |= (v & 0xFF) << (8 * j);
    }
    op[c] = p;
  }
  int4 ov; ov.x = op[0]; ov.y = op[1]; ov.z = op[2]; ov.w = op[3];
  *(int4*)(y1p + pidx * 16 + s * 4) = ov;
}

// ---------------- k23: conv2 (LDS halo) -> y2 in LDS -> conv3 + residual ----------------
// R14: partial unroll. R13's rolled loops fixed I$ thrash (120->76 us,
// VALU 35->57%) but left per-iteration lgkm stalls (compiler doesn't
// pipeline s_loads across rolled iterations). unroll 3 on the 9-tap loop
// (~6 KB body) + unroll 2 on conv3's cc loop: scheduler hoists iteration
// t+1's weight s_loads under iteration t's 256 dot4s; total text ~14 KB,
// still < 32 KB I$.
__global__ __launch_bounds__(256) void k23_conv23(
    const int* __restrict__ y1p,
    const int* __restrict__ w2p,   // [s][tap][cg][cc]
    const float* __restrict__ a2p, const float* __restrict__ o2p,
    const int* __restrict__ w3p,
    const float* __restrict__ a3p, const float* __restrict__ o3p,
    const int* __restrict__ x8p,
    float* __restrict__ out)
{
  __shared__ int4 lds[4 * 58 * 5];   // halo: 18560 B
  __shared__ int ldsy[64 * 20];      // y2 tile: 5120 B

  // bijective XCD swizzle: XCD k runs tiles 196k..196k+195 (contiguous)
  int t0 = (blockIdx.x & 7) * 196 + (blockIdx.x >> 3);
  int n = t0 / 49;
  int bl = t0 - n * 49;
  int p0l = bl * 64;

  int lane = threadIdx.x & 63;
  int s = __builtin_amdgcn_readfirstlane(threadIdx.x >> 6);
  int h0 = p0l / IMGW;

  // ---- stage halo rows h0-1..h0+2, zero-padded; lds[pp*5 + chunk] ----
  const int4* src = (const int4*)y1p;
  int tid = threadIdx.x;
#pragma unroll
  for (int i = 0; i < 4; ++i) {
    int idx = tid + i * 256;
    if (idx < 928) {
      int pp = idx >> 2;
      int chunk = idx & 3;
      int r = pp / 58;
      int col = pp - r * 58;
      int hh = h0 - 1 + r;
      int4 v = make_int4(0, 0, 0, 0);
      if ((unsigned)hh < 56u && col >= 1 && col <= 56)
        v = src[((size_t)n * HW + (size_t)hh * IMGW + (col - 1)) * 4 + chunk];
      lds[pp * 5 + chunk] = v;
    }
  }
  __syncthreads();

  // ---- hoisted residual loads (in flight under conv2) ----
  size_t pg = (size_t)n * HW + p0l + lane;
  int4 rq0, rq1, rq2, rq3;
  {
    const int4* ra = (const int4*)(x8p + pg * 64 + s * 16);
    rq0 = ra[0]; rq1 = ra[1]; rq2 = ra[2]; rq3 = ra[3];
  }

  int posl = p0l + lane;
  int h = posl / IMGW;
  int w = posl - h * IMGW;
  int center = (h - h0 + 1) * 58 + (w + 1);

  // ---- conv2: 9-tap loop, unroll 3 ----
  int acc[16];
#pragma unroll
  for (int i = 0; i < 16; ++i) acc[i] = 0;

  const int4* wq = (const int4*)w2p;

#pragma unroll 3
  for (int t = 0; t < 9; ++t) {
    int ky = t / 3;            // scalar (uniform) arithmetic
    int kx = t - ky * 3;
    int lp2 = center + (ky - 1) * 58 + (kx - 1);
    const int4* xt = &lds[lp2 * 5];
    int4 x0 = xt[0], x1 = xt[1], x2 = xt[2], x3 = xt[3];
    const int4* wt = wq + (s * 9 + t) * 64;
#pragma unroll
    for (int m = 0; m < 4; ++m) {
      int4 xm = m == 0 ? x0 : (m == 1 ? x1 : (m == 2 ? x2 : x3));
#pragma unroll
      for (int e = 0; e < 4; ++e) {
        int xv = e == 0 ? xm.x : (e == 1 ? xm.y : (e == 2 ? xm.z : xm.w));
        const int4* wr = wt + (m * 4 + e) * 4;
#pragma unroll
        for (int cc = 0; cc < 4; ++cc) {
          int4 wv = wr[cc];
          acc[cc * 4 + 0] = dot4i8(xv, wv.x, acc[cc * 4 + 0]);
          acc[cc * 4 + 1] = dot4i8(xv, wv.y, acc[cc * 4 + 1]);
          acc[cc * 4 + 2] = dot4i8(xv, wv.z, acc[cc * 4 + 2]);
          acc[cc * 4 + 3] = dot4i8(xv, wv.w, acc[cc * 4 + 3]);
        }
      }
    }
  }

  // ---- BN+relu -> y2 tile in LDS ----
  {
    int op[4];
#pragma unroll
    for (int c = 0; c < 4; ++c) {
      int p = 0;
#pragma unroll
      for (int j = 0; j < 4; ++j) {
        int co = s * 16 + c * 4 + j;
        float r = bnq(a2p[co], o2p[co], acc[c * 4 + j]);
        int v = (int)r;
        if (v < 0) v = 0;
        p |= (v & 0xFF) << (8 * j);
      }
      op[c] = p;
    }
    int4 ov; ov.x = op[0]; ov.y = op[1]; ov.z = op[2]; ov.w = op[3];
    *(int4*)(&ldsy[lane * 20 + s * 4]) = ov;
  }
  __syncthreads();

  // ---- conv3 + residual + out ----
  int xp[16];
#pragma unroll
  for (int m = 0; m < 4; ++m) {
    int4 xm = *(const int4*)(&ldsy[lane * 20 + m * 4]);
    xp[m * 4 + 0] = xm.x;
    xp[m * 4 + 1] = xm.y;
    xp[m * 4 + 2] = xm.z;
    xp[m * 4 + 3] = xm.w;
  }

#pragma unroll
  for (int m = 0; m < 4; ++m) {       // static: rq[m] stays in registers
    int4 rqm = m == 0 ? rq0 : (m == 1 ? rq1 : (m == 2 ? rq2 : rq3));
#pragma unroll 2
    for (int cc = 0; cc < 4; ++cc) {
      int c4 = m * 4 + cc;
      int co4 = s * 16 + c4;
      const int4* wr = ((const int4*)w3p) + co4 * 16;  // uniform -> s_load
      int ac0 = 0, ac1 = 0, ac2 = 0, ac3 = 0;
#pragma unroll
      for (int cg = 0; cg < 16; ++cg) {
        int4 wv = wr[cg];
        ac0 = dot4i8(xp[cg], wv.x, ac0);
        ac1 = dot4i8(xp[cg], wv.y, ac1);
        ac2 = dot4i8(xp[cg], wv.z, ac2);
        ac3 = dot4i8(xp[cg], wv.w, ac3);
      }

      int ip = cc == 0 ? rqm.x : (cc == 1 ? rqm.y : (cc == 2 ? rqm.z : rqm.w));

      float* ob = out + ((size_t)n * 256 + (size_t)co4 * 4) * HW + posl;
      int accs[4] = {ac0, ac1, ac2, ac3};
#pragma unroll
      for (int j = 0; j < 4; ++j) {
        int co = co4 * 4 + j;
        float r = bnq(a3p[co], o3p[co], accs[j]);
        int id = (int)(int8_t)(ip >> (8 * j));
        int v = (int)r + id;
        v = v > 127 ? 127 : v;
        v = v < 0 ? 0 : v;  // clamp(-128,..) then relu => max(0, min(127, .))
        ob[(size_t)j * HW] = (float)v;
      }
    }
  }
}

extern "C" void kernel_launch(void* const* d_in, const int* in_sizes, int n_in,
                              void* d_out, int out_size, void* d_ws, size_t ws_size,
                              hipStream_t stream) {
  const float* x  = (const float*)d_in[0];
  const int*   s1 = (const int*)d_in[1];
  const int*   m1 = (const int*)d_in[2];
  const float* a1 = (const float*)d_in[3];
  const float* b1 = (const float*)d_in[4];
  const int*   q1 = (const int*)d_in[5];
  const int*   s2 = (const int*)d_in[6];
  const int*   m2 = (const int*)d_in[7];
  const float* a2 = (const float*)d_in[8];
  const float* b2 = (const float*)d_in[9];
  const int*   q2 = (const int*)d_in[10];
  const int*   s3 = (const int*)d_in[11];
  const int*   m3 = (const int*)d_in[12];
  const float* a3 = (const float*)d_in[13];
  const float* b3 = (const float*)d_in[14];
  const int*   q3 = (const int*)d_in[15];

  char* ws = (char*)d_ws;
  int* w1p = (int*)(ws + 0);        // 16384 B
  int* w2p = (int*)(ws + 16384);    // 36864 B
  int* w3p = (int*)(ws + 53248);    // 16384 B
  float* a1p = (float*)(ws + 69632);
  float* o1p = (float*)(ws + 69888);
  float* a2p = (float*)(ws + 70144);
  float* o2p = (float*)(ws + 70400);
  float* a3p = (float*)(ws + 70656);
  float* o3p = (float*)(ws + 71680);
  int* y1p = (int*)(ws + 73728);                       // 6,422,528 B (packed [n][pos][16])
  int* x8p = (int*)(ws + 73728 + 6422528);             // 25,690,112 B (packed [n][pos][64])

  prep_kernel<<<64, 256, 0, stream>>>(s1, m1, a1, b1, q1,
                                      s2, m2, a2, b2, q2,
                                      s3, m3, a3, b3, q3,
                                      w1p, w2p, w3p,
                                      a1p, o1p, a2p, o2p, a3p, o3p);

  k01_pack_conv1<<<(NIMG * HW) / 64, 256, 0, stream>>>(x, w1p, a1p, o1p, x8p, y1p);
  k23_conv23<<<(NIMG * HW) / 64, 256, 0, stream>>>(y1p, w2p, a2p, o2p,
                                                   w3p, a3p, o3p, x8p,
                                                   (float*)d_out);
}

// Round 15
// 64.486 us; speedup vs baseline: 1.7027x; 1.7027x over previous
//
#include <hip/hip_runtime.h>
#include <stdint.h>

#define HW 3136
#define IMGW 56
#define NIMG 32

typedef int i32x4 __attribute__((ext_vector_type(4)));

// BN: round((alpha*acc + off) * 2^-10), clamp to [-128,127]. Exact f32 ops,
// no contraction (matches numpy mul/add/round-half-even chain bit-exactly).
static __device__ __forceinline__ float bnq(float alpha, float off, int acc) {
  float t = __fmul_rn(alpha, (float)acc);
  t = __fadd_rn(t, off);
  t = __fmul_rn(t, 0x1p-10f);
  float r = rintf(t);
  return fminf(fmaxf(r, -128.0f), 127.0f);
}

// ---------------- prep: pack weights into MFMA B-fragments + fold BN ----------------
// B-frag convention (v_mfma_i32_16x16x64_i8): lane l holds B[k=(l>>4)*16+j][col=l&15],
// j = jw*4+b (byte b of int jw). Any consistent k-permutation applied to both A and B
// fragments yields the same dot product, so only A/B AGREEMENT matters; our A source
// layouts are k-consecutive bytes, so B is packed k-consecutive here too.
__global__ void prep_kernel(
    const int* __restrict__ s1, const int* __restrict__ m1,
    const float* __restrict__ a1, const float* __restrict__ b1, const int* __restrict__ q1,
    const int* __restrict__ s2, const int* __restrict__ m2,
    const float* __restrict__ a2, const float* __restrict__ b2, const int* __restrict__ q2,
    const int* __restrict__ s3, const int* __restrict__ m3,
    const float* __restrict__ a3, const float* __restrict__ b3, const int* __restrict__ q3,
    int* __restrict__ w1m, int* __restrict__ w2m, int* __restrict__ w3m,
    float* __restrict__ a1p, float* __restrict__ o1p,
    float* __restrict__ a2p, float* __restrict__ o2p,
    float* __restrict__ a3p, float* __restrict__ o3p)
{
  int t = blockIdx.x * blockDim.x + threadIdx.x;
  int nthr = gridDim.x * blockDim.x;

  // w1m[((kk*4+s)*64+l)*4+jw]: conv1 B-frag for K-step kk (ci kk*64..+63), col co=s*16+(l&15)
  for (int i = t; i < 4096; i += nthr) {
    int jw = i & 3, l = (i >> 2) & 63;
    int rest = i >> 8;              // kk*4+s
    int s = rest & 3, kk = rest >> 2;
    int c = l & 15, g = l >> 4;
    int co = s * 16 + c;
    int p = 0;
    for (int b = 0; b < 4; ++b) {
      int ci = kk * 64 + g * 16 + jw * 4 + b;
      int idx = co * 256 + ci;
      int w = m1[idx] * (1 << s1[idx]);
      p |= (w & 0xFF) << (8 * b);
    }
    w1m[i] = p;
  }
  // w2m[((tap*4+s)*64+l)*4+jw]: conv2 B-frag per tap, ci=(l>>4)*16+jw*4+b, co=s*16+(l&15)
  for (int i = t; i < 9216; i += nthr) {
    int jw = i & 3, l = (i >> 2) & 63;
    int rest = i >> 8;              // tap*4+s
    int s = rest & 3, tap = rest >> 2;
    int c = l & 15, g = l >> 4;
    int co = s * 16 + c;
    int ky = tap / 3, kx = tap - ky * 3;
    int p = 0;
    for (int b = 0; b < 4; ++b) {
      int ci = g * 16 + jw * 4 + b;
      int idx = ((co * 64 + ci) * 3 + ky) * 3 + kx;
      int w = m2[idx] * (1 << s2[idx]);
      p |= (w & 0xFF) << (8 * b);
    }
    w2m[i] = p;
  }
  // w3m[((s*4+nt)*64+l)*4+jw]: conv3 B-frag, co=s*64+nt*16+(l&15), ci=(l>>4)*16+jw*4+b
  for (int i = t; i < 4096; i += nthr) {
    int jw = i & 3, l = (i >> 2) & 63;
    int rest = i >> 8;              // s*4+nt
    int nt = rest & 3, s = rest >> 2;
    int c = l & 15, g = l >> 4;
    int co = s * 64 + nt * 16 + c;
    int p = 0;
    for (int b = 0; b < 4; ++b) {
      int ci = g * 16 + jw * 4 + b;
      int idx = co * 64 + ci;
      int w = m3[idx] * (1 << s3[idx]);
      p |= (w & 0xFF) << (8 * b);
    }
    w3m[i] = p;
  }
  for (int i = t; i < 64; i += nthr) {
    a1p[i] = a1[i];
    o1p[i] = __fmul_rn(b1[i], exp2f((float)q1[i] + 10.0f));
    a2p[i] = a2[i];
    o2p[i] = __fmul_rn(b2[i], exp2f((float)q2[i] + 10.0f));
  }
  for (int i = t; i < 256; i += nthr) {
    a3p[i] = a3[i];
    o3p[i] = __fmul_rn(b3[i], exp2f((float)q3[i] + 10.0f));
  }
}

// ---------------- k01: pack x -> int8 (x8p + LDS), then conv1 via MFMA ----------------
// Phase A unchanged (R6 pattern). Phase B: wave s computes co s*16..+15 for the
// block's 64 pos as 4 M-tiles x 4 K-steps of mfma_i32_16x16x64_i8.
// A-frag: lane l reads ldsx[(mt*16+(l&15))*68 + kk*16 + (l>>4)*4] (16B, aligned).
// D: col(co)=l&15, row(pos)=(l>>4)*4+reg -> BN with per-lane alpha, byte-store y1.
__global__ __launch_bounds__(256) void k01_pack_conv1(
    const float* __restrict__ x,
    const int* __restrict__ w1m,
    const float* __restrict__ a1p, const float* __restrict__ o1p,
    int* __restrict__ x8p, int* __restrict__ y1p)
{
  __shared__ int ldsx[64 * 68];   // 17408 B

  int tid = threadIdx.x;

  // ---- Phase A: load + pack ----
  {
    int o = tid & 3;
    int p = tid >> 2;
    size_t pg = (size_t)blockIdx.x * 64 + p;
    int n = (int)(pg / HW);
    int pos = (int)(pg - (size_t)n * HW);
    const float* xb = x + ((size_t)n * 256 + o * 64) * HW + pos;

    float f[64];
#pragma unroll
    for (int k = 0; k < 64; ++k) f[k] = xb[(size_t)k * HW];
    __builtin_amdgcn_sched_barrier(0);  // all 64 loads before any consumer

    int4 ov[4];
#pragma unroll
    for (int g = 0; g < 4; ++g) {
      int wds[4];
#pragma unroll
      for (int wdi = 0; wdi < 4; ++wdi) {
        int c0 = g * 16 + wdi * 4;
        wds[wdi] = ((int)f[c0] & 0xFF) | (((int)f[c0 + 1] & 0xFF) << 8) |
                   (((int)f[c0 + 2] & 0xFF) << 16) | (((int)f[c0 + 3] & 0xFF) << 24);
      }
      ov[g].x = wds[0]; ov[g].y = wds[1]; ov[g].z = wds[2]; ov[g].w = wds[3];
    }

    int* gb = x8p + pg * 64 + o * 16;
#pragma unroll
    for (int g = 0; g < 4; ++g) ((int4*)gb)[g] = ov[g];
    int* lb = &ldsx[p * 68 + o * 16];
#pragma unroll
    for (int g = 0; g < 4; ++g) *(int4*)(lb + g * 4) = ov[g];
  }
  __syncthreads();

  // ---- Phase B: conv1 MFMA ----
  int lane = tid & 63;
  int sW = __builtin_amdgcn_readfirstlane(tid >> 6);
  int c = lane & 15, g = lane >> 4;

  i32x4 acc[4];
#pragma unroll
  for (int mt = 0; mt < 4; ++mt) acc[mt] = (i32x4){0, 0, 0, 0};

#pragma unroll
  for (int kk = 0; kk < 4; ++kk) {
    i32x4 bf = *(const i32x4*)(w1m + ((kk * 4 + sW) * 64 + lane) * 4);
#pragma unroll
    for (int mt = 0; mt < 4; ++mt) {
      i32x4 af = *(const i32x4*)(ldsx + (mt * 16 + c) * 68 + kk * 16 + g * 4);
      acc[mt] = __builtin_amdgcn_mfma_i32_16x16x64_i8(af, bf, acc[mt], 0, 0, 0);
    }
  }

  float al = a1p[sW * 16 + c], of = o1p[sW * 16 + c];
  char* yb = (char*)y1p;
  size_t pb = (size_t)blockIdx.x * 64;
#pragma unroll
  for (int mt = 0; mt < 4; ++mt) {
#pragma unroll
    for (int r = 0; r < 4; ++r) {
      float rv = bnq(al, of, acc[mt][r]);
      int v = (int)rv;
      if (v < 0) v = 0;  // relu
      yb[(pb + mt * 16 + g * 4 + r) * 64 + sW * 16 + c] = (char)v;
    }
  }
}

// ---------------- k23: conv2 + conv3 via MFMA ----------------
// conv2: 9 taps, each one mfma per M-tile (K=64), A from halo LDS (stride 5 int4,
// conflict-free), B-frags from w2m. D -> BN (per-lane alpha) -> int8 bytes into
// ldsy [64 pos][80B]. conv3: per nt (16-co column): 4 mfma, D transposed through
// a per-wave LDS region (stride 20 ints, aliased over the dead halo) so the
// epilogue keeps lane=pos with s_load BN constants + residual + f32 stores.
__global__ __launch_bounds__(256) void k23_conv23(
    const int* __restrict__ y1p,
    const int* __restrict__ w2m,
    const float* __restrict__ a2p, const float* __restrict__ o2p,
    const int* __restrict__ w3m,
    const float* __restrict__ a3p, const float* __restrict__ o3p,
    const int* __restrict__ x8p,
    float* __restrict__ out)
{
  __shared__ __align__(16) char smem[25600];
  int4* halo = (int4*)smem;            // [232 pp][5 int4] = 18560 B (dead after conv2)
  char* ldsyB = smem + 20480;          // y2 tile [64 pos][80 B] = 5120 B

  // bijective XCD swizzle: XCD k runs tiles 196k..196k+195
  int t0 = (blockIdx.x & 7) * 196 + (blockIdx.x >> 3);
  int n = t0 / 49;
  int bl = t0 - n * 49;
  int p0l = bl * 64;

  int tid = threadIdx.x;
  int lane = tid & 63;
  int sW = __builtin_amdgcn_readfirstlane(tid >> 6);
  int h0 = p0l / IMGW;

  // ---- stage halo rows h0-1..h0+2, zero-padded ----
  const int4* src = (const int4*)y1p;
#pragma unroll
  for (int i = 0; i < 4; ++i) {
    int idx = tid + i * 256;
    if (idx < 928) {
      int pp = idx >> 2, chunk = idx & 3;
      int r = pp / 58, col = pp - r * 58;
      int hh = h0 - 1 + r;
      int4 v = make_int4(0, 0, 0, 0);
      if ((unsigned)hh < 56u && col >= 1 && col <= 56)
        v = src[((size_t)n * HW + (size_t)hh * IMGW + (col - 1)) * 4 + chunk];
      halo[pp * 5 + chunk] = v;
    }
  }

  // ---- hoisted residual loads (co sW*64..+63 for pos p0l+lane) ----
  size_t pg = (size_t)n * HW + p0l + lane;
  const i32x4* ra = (const i32x4*)(x8p + pg * 64 + sW * 16);
  i32x4 rq0 = ra[0], rq1 = ra[1], rq2 = ra[2], rq3 = ra[3];

  __syncthreads();

  int c = lane & 15, g = lane >> 4;

  int cen[4];
#pragma unroll
  for (int mt = 0; mt < 4; ++mt) {
    int pos = p0l + mt * 16 + c;
    int hh = pos / IMGW, ww = pos - hh * IMGW;
    cen[mt] = (hh - h0 + 1) * 58 + ww + 1;
  }

  // ---- conv2 MFMA: 9 taps x 4 M-tiles ----
  i32x4 acc[4];
#pragma unroll
  for (int mt = 0; mt < 4; ++mt) acc[mt] = (i32x4){0, 0, 0, 0};

#pragma unroll
  for (int tap = 0; tap < 9; ++tap) {
    i32x4 bf = *(const i32x4*)(w2m + ((tap * 4 + sW) * 64 + lane) * 4);
    int ky = tap / 3, kx = tap - ky * 3;
    int d = (ky - 1) * 58 + (kx - 1);
#pragma unroll
    for (int mt = 0; mt < 4; ++mt) {
      i32x4 af = *(const i32x4*)&halo[(cen[mt] + d) * 5 + g];
      acc[mt] = __builtin_amdgcn_mfma_i32_16x16x64_i8(af, bf, acc[mt], 0, 0, 0);
    }
  }

  // ---- BN+relu -> int8 into ldsy (A-layout for conv3) ----
  {
    float al = a2p[sW * 16 + c], of = o2p[sW * 16 + c];
#pragma unroll
    for (int mt = 0; mt < 4; ++mt) {
#pragma unroll
      for (int r = 0; r < 4; ++r) {
        float rv = bnq(al, of, acc[mt][r]);
        int v = (int)rv;
        if (v < 0) v = 0;
        ldsyB[(mt * 16 + g * 4 + r) * 80 + sW * 16 + c] = (char)v;
      }
    }
  }
  __syncthreads();

  // ---- conv3 MFMA + transpose-through-LDS epilogue ----
  int* Dw = (int*)smem + sW * 1280;    // per-wave D region: [64 pos][20 ints]
  int posl = p0l + lane;
  float* ob = out + (size_t)n * 256 * HW + posl;

#pragma unroll
  for (int nt = 0; nt < 4; ++nt) {
    i32x4 bf = *(const i32x4*)(w3m + ((sW * 4 + nt) * 64 + lane) * 4);
#pragma unroll
    for (int mt = 0; mt < 4; ++mt) {
      i32x4 af = *(const i32x4*)(ldsyB + (mt * 16 + c) * 80 + g * 16);
      i32x4 z = {0, 0, 0, 0};
      i32x4 D = __builtin_amdgcn_mfma_i32_16x16x64_i8(af, bf, z, 0, 0, 0);
      Dw[(mt * 16 + g * 4 + 0) * 20 + c] = D[0];
      Dw[(mt * 16 + g * 4 + 1) * 20 + c] = D[1];
      Dw[(mt * 16 + g * 4 + 2) * 20 + c] = D[2];
      Dw[(mt * 16 + g * 4 + 3) * 20 + c] = D[3];
    }
    // same-wave LDS write->read: in-order through the LDS pipe (lgkmcnt by compiler)
    i32x4 q0 = *(const i32x4*)(Dw + lane * 20 + 0);
    i32x4 q1 = *(const i32x4*)(Dw + lane * 20 + 4);
    i32x4 q2 = *(const i32x4*)(Dw + lane * 20 + 8);
    i32x4 q3 = *(const i32x4*)(Dw + lane * 20 + 12);
    i32x4 rqn = nt == 0 ? rq0 : (nt == 1 ? rq1 : (nt == 2 ? rq2 : rq3));
#pragma unroll
    for (int cc = 0; cc < 16; ++cc) {
      int accv = cc < 4 ? q0[cc] : cc < 8 ? q1[cc - 4] : cc < 12 ? q2[cc - 8] : q3[cc - 12];
      int co = sW * 64 + nt * 16 + cc;                 // wave-uniform -> s_load BN consts
      float rv = bnq(a3p[co], o3p[co], accv);
      int ip = rqn[cc >> 2];
      int id = (int)(int8_t)(ip >> (8 * (cc & 3)));
      int v = (int)rv + id;
      v = v > 127 ? 127 : v;
      v = v < 0 ? 0 : v;  // clamp(-128,..) then relu => max(0, min(127, .))
      ob[(size_t)co * HW] = (float)v;
    }
  }
}

extern "C" void kernel_launch(void* const* d_in, const int* in_sizes, int n_in,
                              void* d_out, int out_size, void* d_ws, size_t ws_size,
                              hipStream_t stream) {
  const float* x  = (const float*)d_in[0];
  const int*   s1 = (const int*)d_in[1];
  const int*   m1 = (const int*)d_in[2];
  const float* a1 = (const float*)d_in[3];
  const float* b1 = (const float*)d_in[4];
  const int*   q1 = (const int*)d_in[5];
  const int*   s2 = (const int*)d_in[6];
  const int*   m2 = (const int*)d_in[7];
  const float* a2 = (const float*)d_in[8];
  const float* b2 = (const float*)d_in[9];
  const int*   q2 = (const int*)d_in[10];
  const int*   s3 = (const int*)d_in[11];
  const int*   m3 = (const int*)d_in[12];
  const float* a3 = (const float*)d_in[13];
  const float* b3 = (const float*)d_in[14];
  const int*   q3 = (const int*)d_in[15];

  char* ws = (char*)d_ws;
  int* w1m = (int*)(ws + 0);        // 16384 B
  int* w2m = (int*)(ws + 16384);    // 36864 B
  int* w3m = (int*)(ws + 53248);    // 16384 B
  float* a1p = (float*)(ws + 69632);
  float* o1p = (float*)(ws + 69888);
  float* a2p = (float*)(ws + 70144);
  float* o2p = (float*)(ws + 70400);
  float* a3p = (float*)(ws + 70656);
  float* o3p = (float*)(ws + 71680);
  int* y1p = (int*)(ws + 73728);                       // 6,422,528 B (packed [n][pos][16])
  int* x8p = (int*)(ws + 73728 + 6422528);             // 25,690,112 B (packed [n][pos][64])

  prep_kernel<<<64, 256, 0, stream>>>(s1, m1, a1, b1, q1,
                                      s2, m2, a2, b2, q2,
                                      s3, m3, a3, b3, q3,
                                      w1m, w2m, w3m,
                                      a1p, o1p, a2p, o2p, a3p, o3p);

  k01_pack_conv1<<<(NIMG * HW) / 64, 256, 0, stream>>>(x, w1m, a1p, o1p, x8p, y1p);
  k23_conv23<<<(NIMG * HW) / 64, 256, 0, stream>>>(y1p, w2m, a2p, o2p,
                                                   w3m, a3p, o3p, x8p,
                                                   (float*)d_out);
}